// Round 2
// baseline (812.137 us; speedup 1.0000x reference)
//
#include <hip/hip_runtime.h>
#include <hip/hip_bf16.h>

#define D 64

// Kernel 1: m[n][64] = relu(x[n][:] @ W + b)   (per-node MLP, pulled out of the edge loop)
__global__ __launch_bounds__(256) void node_mlp_kernel(
    const float* __restrict__ x, const float* __restrict__ W,
    const float* __restrict__ b, float* __restrict__ m, int n_nodes) {
    __shared__ float Ws[D * D];
    __shared__ float bs[D];
    for (int i = threadIdx.x; i < D * D; i += 256) Ws[i] = W[i];
    if (threadIdx.x < D) bs[threadIdx.x] = b[threadIdx.x];
    __syncthreads();

    const int lane = threadIdx.x & 63;
    const int rowInBlk = threadIdx.x >> 6;  // 4 rows per 256-thread block

    for (int row = blockIdx.x * 4 + rowInBlk; row < n_nodes; row += gridDim.x * 4) {
        float xr = x[row * D + lane];   // lane l holds x[row][l]
        float acc = bs[lane];
        #pragma unroll
        for (int k = 0; k < D; ++k) {
            float a = __shfl(xr, k);               // broadcast x[row][k] across the wave
            acc = fmaf(a, Ws[k * D + lane], acc);  // stride-1 LDS: conflict-free
        }
        m[row * D + lane] = fmaxf(acc, 0.0f);
    }
}

// Kernel 2: for each edge e: out[dst[e]][:] += m[src[e]][:]
// 16 threads per edge, each owns 4 contiguous floats (float4 gather + 4 atomics).
__global__ __launch_bounds__(256) void edge_scatter_kernel(
    const int* __restrict__ src, const int* __restrict__ dst,
    const float* __restrict__ m, float* __restrict__ out, int n_edges) {
    long long t = (long long)blockIdx.x * blockDim.x + threadIdx.x;
    int e = (int)(t >> 4);
    if (e >= n_edges) return;
    int c = (int)(t & 15) << 2;  // column offset 0..60 step 4

    int s = src[e];
    int d = dst[e];
    const float4 v = *(const float4*)(m + (size_t)s * D + c);
    float* o = out + (size_t)d * D + c;
    atomicAdd(o + 0, v.x);
    atomicAdd(o + 1, v.y);
    atomicAdd(o + 2, v.z);
    atomicAdd(o + 3, v.w);
}

extern "C" void kernel_launch(void* const* d_in, const int* in_sizes, int n_in,
                              void* d_out, int out_size, void* d_ws, size_t ws_size,
                              hipStream_t stream) {
    const float* x = (const float*)d_in[0];
    const int* edge_index = (const int*)d_in[1];   // harness delivers integer inputs as int32
    const float* W = (const float*)d_in[2];
    const float* b = (const float*)d_in[3];
    float* out = (float*)d_out;

    const int n_nodes = in_sizes[0] / D;        // 50000
    const int n_edges = in_sizes[1] / 2;        // 800000
    const int* src = edge_index;                // row 0 (j, gather)
    const int* dst = edge_index + n_edges;      // row 1 (i, scatter)

    float* m = (float*)d_ws;  // n_nodes * D floats = 12.8 MB

    // out is poisoned to 0xAA before each timed launch — zero it (async, capturable).
    hipMemsetAsync(d_out, 0, (size_t)out_size * sizeof(float), stream);

    // Node MLP: 4 rows/block
    int mlp_blocks = (n_nodes + 3) / 4;
    node_mlp_kernel<<<mlp_blocks, 256, 0, stream>>>(x, W, b, m, n_nodes);

    // Edge scatter: 16 threads per edge
    long long total_threads = (long long)n_edges * 16;
    int scat_blocks = (int)((total_threads + 255) / 256);
    edge_scatter_kernel<<<scat_blocks, 256, 0, stream>>>(src, dst, m, out, n_edges);
}

// Round 3
// 380.447 us; speedup vs baseline: 2.1347x; 2.1347x over previous
//
#include <hip/hip_runtime.h>
#include <hip/hip_bf16.h>

#define D 64

// ---------- Kernel 1: m[n][:] = relu(x[n][:] @ W + b) ----------
__global__ __launch_bounds__(256) void node_mlp_kernel(
    const float* __restrict__ x, const float* __restrict__ W,
    const float* __restrict__ b, float* __restrict__ m, int n_nodes) {
    __shared__ float Ws[D * D];
    __shared__ float bs[D];
    for (int i = threadIdx.x; i < D * D; i += 256) Ws[i] = W[i];
    if (threadIdx.x < D) bs[threadIdx.x] = b[threadIdx.x];
    __syncthreads();

    const int lane = threadIdx.x & 63;
    const int rowInBlk = threadIdx.x >> 6;  // 4 rows per 256-thread block

    for (int row = blockIdx.x * 4 + rowInBlk; row < n_nodes; row += gridDim.x * 4) {
        float xr = x[(size_t)row * D + lane];
        float acc = bs[lane];
        #pragma unroll
        for (int k = 0; k < D; ++k) {
            float a = __shfl(xr, k);
            acc = fmaf(a, Ws[k * D + lane], acc);
        }
        m[(size_t)row * D + lane] = fmaxf(acc, 0.0f);
    }
}

// ---------- Kernel 2: histogram of dst ----------
__global__ __launch_bounds__(256) void hist_kernel(
    const int* __restrict__ dst, int* __restrict__ counts, int n_edges) {
    int e = blockIdx.x * 256 + threadIdx.x;
    if (e < n_edges) atomicAdd(&counts[dst[e]], 1);
}

// ---------- Kernel 3: exclusive scan (single 1024-thread block) ----------
__global__ __launch_bounds__(1024) void scan_kernel(
    const int* __restrict__ counts, int* __restrict__ offsets,
    int* __restrict__ cursor, int n) {
    __shared__ int part[1024];
    int t = threadIdx.x;
    int chunk = (n + 1023) / 1024;
    int beg = t * chunk;
    int end = min(beg + chunk, n);
    int s = 0;
    for (int i = beg; i < end; ++i) s += counts[i];
    part[t] = s;
    __syncthreads();
    // Hillis-Steele inclusive scan over 1024 partials
    for (int off = 1; off < 1024; off <<= 1) {
        int v = (t >= off) ? part[t - off] : 0;
        __syncthreads();
        part[t] += v;
        __syncthreads();
    }
    int run = (t == 0) ? 0 : part[t - 1];  // exclusive prefix of this chunk
    for (int i = beg; i < end; ++i) {
        offsets[i] = run;
        cursor[i] = run;
        run += counts[i];
    }
    if (t == 1023) offsets[n] = part[1023];
}

// ---------- Kernel 4: scatter src into dst-grouped order ----------
__global__ __launch_bounds__(256) void scatter_kernel(
    const int* __restrict__ src, const int* __restrict__ dst,
    int* __restrict__ cursor, int* __restrict__ sorted_src, int n_edges) {
    int e = blockIdx.x * 256 + threadIdx.x;
    if (e >= n_edges) return;
    int d = dst[e];
    int pos = atomicAdd(&cursor[d], 1);
    sorted_src[pos] = src[e];
}

// ---------- Kernel 5: one wave per dst node — register accumulate, plain store ----------
__global__ __launch_bounds__(256) void gather_accum_kernel(
    const int* __restrict__ sorted_src, const int* __restrict__ offsets,
    const float* __restrict__ m, float* __restrict__ out, int n_nodes) {
    int node = blockIdx.x * 4 + (threadIdx.x >> 6);
    if (node >= n_nodes) return;
    int lane = threadIdx.x & 63;

    int beg = offsets[node];
    int cnt = offsets[node + 1] - beg;
    float acc = 0.0f;
    for (int base = 0; base < cnt; base += 64) {
        int idx = (base + lane < cnt) ? sorted_src[beg + base + lane] : 0;
        int lim = min(64, cnt - base);
        for (int k = 0; k < lim; ++k) {
            int s = __shfl(idx, k);
            acc += m[(size_t)s * D + lane];   // 256B coalesced row, L2/L3-resident
        }
    }
    out[(size_t)node * D + lane] = acc;
}

// ---------- Fallback: atomic scatter (if ws too small) ----------
__global__ __launch_bounds__(256) void edge_scatter_kernel(
    const int* __restrict__ src, const int* __restrict__ dst,
    const float* __restrict__ m, float* __restrict__ out, int n_edges) {
    long long t = (long long)blockIdx.x * blockDim.x + threadIdx.x;
    int e = (int)(t >> 4);
    if (e >= n_edges) return;
    int c = (int)(t & 15) << 2;
    int s = src[e];
    int d = dst[e];
    const float4 v = *(const float4*)(m + (size_t)s * D + c);
    float* o = out + (size_t)d * D + c;
    atomicAdd(o + 0, v.x);
    atomicAdd(o + 1, v.y);
    atomicAdd(o + 2, v.z);
    atomicAdd(o + 3, v.w);
}

static inline size_t align_up(size_t v, size_t a) { return (v + a - 1) & ~(a - 1); }

extern "C" void kernel_launch(void* const* d_in, const int* in_sizes, int n_in,
                              void* d_out, int out_size, void* d_ws, size_t ws_size,
                              hipStream_t stream) {
    const float* x = (const float*)d_in[0];
    const int* edge_index = (const int*)d_in[1];   // int32 per harness contract
    const float* W = (const float*)d_in[2];
    const float* b = (const float*)d_in[3];
    float* out = (float*)d_out;

    const int n_nodes = in_sizes[0] / D;        // 50000
    const int n_edges = in_sizes[1] / 2;        // 800000
    const int* src = edge_index;                // row 0 (j, gather)
    const int* dst = edge_index + n_edges;      // row 1 (i, scatter)

    // Workspace layout
    size_t off = 0;
    float* m = (float*)((char*)d_ws + off);
    off = align_up(off + (size_t)n_nodes * D * sizeof(float), 256);
    int* counts = (int*)((char*)d_ws + off);
    off = align_up(off + (size_t)n_nodes * sizeof(int), 256);
    int* offsets = (int*)((char*)d_ws + off);
    off = align_up(off + ((size_t)n_nodes + 1) * sizeof(int), 256);
    int* cursor = (int*)((char*)d_ws + off);
    off = align_up(off + (size_t)n_nodes * sizeof(int), 256);
    int* sorted_src = (int*)((char*)d_ws + off);
    off = align_up(off + (size_t)n_edges * sizeof(int), 256);
    const size_t needed = off;

    // Node MLP (needed by both paths)
    int mlp_blocks = (n_nodes + 3) / 4;
    node_mlp_kernel<<<mlp_blocks, 256, 0, stream>>>(x, W, b, m, n_nodes);

    if (ws_size >= needed) {
        // CSR build + per-node accumulate (atomic-free output)
        hipMemsetAsync(counts, 0, (size_t)n_nodes * sizeof(int), stream);
        int eblocks = (n_edges + 255) / 256;
        hist_kernel<<<eblocks, 256, 0, stream>>>(dst, counts, n_edges);
        scan_kernel<<<1, 1024, 0, stream>>>(counts, offsets, cursor, n_nodes);
        scatter_kernel<<<eblocks, 256, 0, stream>>>(src, dst, cursor, sorted_src, n_edges);
        gather_accum_kernel<<<(n_nodes + 3) / 4, 256, 0, stream>>>(
            sorted_src, offsets, m, out, n_nodes);
    } else {
        // Fallback: atomic scatter path
        hipMemsetAsync(d_out, 0, (size_t)out_size * sizeof(float), stream);
        long long total_threads = (long long)n_edges * 16;
        int scat_blocks = (int)((total_threads + 255) / 256);
        edge_scatter_kernel<<<scat_blocks, 256, 0, stream>>>(src, dst, m, out, n_edges);
    }
}

// Round 4
// 279.306 us; speedup vs baseline: 2.9077x; 1.3621x over previous
//
#include <hip/hip_runtime.h>
#include <hip/hip_bf16.h>

#define D 64
#define SCAN_TILE 1024   // elements per scan block (256 threads x 4)

// ---------- Kernel 1: m[n][:] = relu(x[n][:] @ W + b) ----------
__global__ __launch_bounds__(256) void node_mlp_kernel(
    const float* __restrict__ x, const float* __restrict__ W,
    const float* __restrict__ b, float* __restrict__ m, int n_nodes) {
    __shared__ float Ws[D * D];
    __shared__ float bs[D];
    for (int i = threadIdx.x; i < D * D; i += 256) Ws[i] = W[i];
    if (threadIdx.x < D) bs[threadIdx.x] = b[threadIdx.x];
    __syncthreads();

    const int lane = threadIdx.x & 63;
    const int rowInBlk = threadIdx.x >> 6;

    for (int row = blockIdx.x * 4 + rowInBlk; row < n_nodes; row += gridDim.x * 4) {
        float xr = x[(size_t)row * D + lane];
        float acc = bs[lane];
        #pragma unroll
        for (int k = 0; k < D; ++k) {
            float a = __shfl(xr, k);
            acc = fmaf(a, Ws[k * D + lane], acc);
        }
        m[(size_t)row * D + lane] = fmaxf(acc, 0.0f);
    }
}

// ---------- Kernel 2: histogram of dst ----------
__global__ __launch_bounds__(256) void hist_kernel(
    const int* __restrict__ dst, int* __restrict__ counts, int n_edges) {
    int e = blockIdx.x * 256 + threadIdx.x;
    if (e < n_edges) atomicAdd(&counts[dst[e]], 1);
}

// ---------- Scan stage 1: per-tile partial sums ----------
__global__ __launch_bounds__(256) void scan_partial_kernel(
    const int* __restrict__ counts, int* __restrict__ partials, int n) {
    __shared__ int red[4];
    int blk = blockIdx.x;
    int t = threadIdx.x;
    int base = blk * SCAN_TILE + t * 4;
    int s = 0;
    #pragma unroll
    for (int i = 0; i < 4; ++i) {
        int idx = base + i;
        if (idx < n) s += counts[idx];
    }
    // wave reduce
    #pragma unroll
    for (int off = 32; off > 0; off >>= 1) s += __shfl_down(s, off);
    if ((t & 63) == 0) red[t >> 6] = s;
    __syncthreads();
    if (t == 0) partials[blk] = red[0] + red[1] + red[2] + red[3];
}

// ---------- Scan stage 2: exclusive scan of tile partials (single small block) ----------
__global__ __launch_bounds__(256) void scan_tops_kernel(
    int* __restrict__ partials, int* __restrict__ total_out, int nb, int n_nodes) {
    __shared__ int part[256];
    int t = threadIdx.x;
    int chunk = (nb + 255) / 256;
    int beg = t * chunk;
    int end = min(beg + chunk, nb);
    int s = 0;
    for (int i = beg; i < end; ++i) s += partials[i];
    part[t] = s;
    __syncthreads();
    for (int off = 1; off < 256; off <<= 1) {
        int v = (t >= off) ? part[t - off] : 0;
        __syncthreads();
        part[t] += v;
        __syncthreads();
    }
    int run = (t == 0) ? 0 : part[t - 1];
    for (int i = beg; i < end; ++i) {
        int c = partials[i];
        partials[i] = run;   // now exclusive prefix
        run += c;
    }
    if (t == 255) total_out[n_nodes] = part[255];  // offsets[n] = E
}

// ---------- Scan stage 3: local exclusive scan + tile offset -> offsets & cursor ----------
__global__ __launch_bounds__(256) void scan_final_kernel(
    const int* __restrict__ counts, const int* __restrict__ partials,
    int* __restrict__ offsets, int* __restrict__ cursor, int n) {
    __shared__ int tsum[256];
    int blk = blockIdx.x;
    int t = threadIdx.x;
    int base = blk * SCAN_TILE + t * 4;
    int c[4];
    int s = 0;
    #pragma unroll
    for (int i = 0; i < 4; ++i) {
        int idx = base + i;
        c[i] = (idx < n) ? counts[idx] : 0;
        s += c[i];
    }
    tsum[t] = s;
    __syncthreads();
    for (int off = 1; off < 256; off <<= 1) {
        int v = (t >= off) ? tsum[t - off] : 0;
        __syncthreads();
        tsum[t] += v;
        __syncthreads();
    }
    int run = partials[blk] + ((t == 0) ? 0 : tsum[t - 1]);
    #pragma unroll
    for (int i = 0; i < 4; ++i) {
        int idx = base + i;
        if (idx < n) {
            offsets[idx] = run;
            cursor[idx] = run;
            run += c[i];
        }
    }
}

// ---------- Kernel 4: scatter src into dst-grouped order ----------
__global__ __launch_bounds__(256) void scatter_kernel(
    const int* __restrict__ src, const int* __restrict__ dst,
    int* __restrict__ cursor, int* __restrict__ sorted_src, int n_edges) {
    int e = blockIdx.x * 256 + threadIdx.x;
    if (e >= n_edges) return;
    int d = dst[e];
    int pos = atomicAdd(&cursor[d], 1);
    sorted_src[pos] = src[e];
}

// ---------- Kernel 5: one wave per dst node — register accumulate, plain store ----------
__global__ __launch_bounds__(256) void gather_accum_kernel(
    const int* __restrict__ sorted_src, const int* __restrict__ offsets,
    const float* __restrict__ m, float* __restrict__ out, int n_nodes) {
    int node = blockIdx.x * 4 + (threadIdx.x >> 6);
    if (node >= n_nodes) return;
    int lane = threadIdx.x & 63;

    int beg = offsets[node];
    int cnt = offsets[node + 1] - beg;
    float acc = 0.0f;
    for (int base = 0; base < cnt; base += 64) {
        int idx = (base + lane < cnt) ? sorted_src[beg + base + lane] : 0;
        int lim = min(64, cnt - base);
        for (int k = 0; k < lim; ++k) {
            int s = __shfl(idx, k);
            acc += m[(size_t)s * D + lane];   // 256B coalesced row, L2/L3-resident
        }
    }
    out[(size_t)node * D + lane] = acc;
}

// ---------- Fallback: atomic scatter (if ws too small) ----------
__global__ __launch_bounds__(256) void edge_scatter_kernel(
    const int* __restrict__ src, const int* __restrict__ dst,
    const float* __restrict__ m, float* __restrict__ out, int n_edges) {
    long long t = (long long)blockIdx.x * blockDim.x + threadIdx.x;
    int e = (int)(t >> 4);
    if (e >= n_edges) return;
    int c = (int)(t & 15) << 2;
    int s = src[e];
    int d = dst[e];
    const float4 v = *(const float4*)(m + (size_t)s * D + c);
    float* o = out + (size_t)d * D + c;
    atomicAdd(o + 0, v.x);
    atomicAdd(o + 1, v.y);
    atomicAdd(o + 2, v.z);
    atomicAdd(o + 3, v.w);
}

static inline size_t align_up(size_t v, size_t a) { return (v + a - 1) & ~(a - 1); }

extern "C" void kernel_launch(void* const* d_in, const int* in_sizes, int n_in,
                              void* d_out, int out_size, void* d_ws, size_t ws_size,
                              hipStream_t stream) {
    const float* x = (const float*)d_in[0];
    const int* edge_index = (const int*)d_in[1];   // int32 per harness contract
    const float* W = (const float*)d_in[2];
    const float* b = (const float*)d_in[3];
    float* out = (float*)d_out;

    const int n_nodes = in_sizes[0] / D;        // 50000
    const int n_edges = in_sizes[1] / 2;        // 800000
    const int* src = edge_index;                // row 0 (j, gather)
    const int* dst = edge_index + n_edges;      // row 1 (i, scatter)

    const int n_tiles = (n_nodes + SCAN_TILE - 1) / SCAN_TILE;

    // Workspace layout
    size_t off = 0;
    float* m = (float*)((char*)d_ws + off);
    off = align_up(off + (size_t)n_nodes * D * sizeof(float), 256);
    int* counts = (int*)((char*)d_ws + off);
    off = align_up(off + (size_t)n_nodes * sizeof(int), 256);
    int* offsets = (int*)((char*)d_ws + off);
    off = align_up(off + ((size_t)n_nodes + 1) * sizeof(int), 256);
    int* cursor = (int*)((char*)d_ws + off);
    off = align_up(off + (size_t)n_nodes * sizeof(int), 256);
    int* sorted_src = (int*)((char*)d_ws + off);
    off = align_up(off + (size_t)n_edges * sizeof(int), 256);
    int* partials = (int*)((char*)d_ws + off);
    off = align_up(off + (size_t)n_tiles * sizeof(int), 256);
    const size_t needed = off;

    // Node MLP (needed by both paths)
    int mlp_blocks = (n_nodes + 3) / 4;
    node_mlp_kernel<<<mlp_blocks, 256, 0, stream>>>(x, W, b, m, n_nodes);

    if (ws_size >= needed) {
        hipMemsetAsync(counts, 0, (size_t)n_nodes * sizeof(int), stream);
        int eblocks = (n_edges + 255) / 256;
        hist_kernel<<<eblocks, 256, 0, stream>>>(dst, counts, n_edges);
        // Hierarchical scan (grid-parallel, replaces 111us single-block scan)
        scan_partial_kernel<<<n_tiles, 256, 0, stream>>>(counts, partials, n_nodes);
        scan_tops_kernel<<<1, 256, 0, stream>>>(partials, offsets, n_tiles, n_nodes);
        scan_final_kernel<<<n_tiles, 256, 0, stream>>>(counts, partials, offsets, cursor, n_nodes);
        scatter_kernel<<<eblocks, 256, 0, stream>>>(src, dst, cursor, sorted_src, n_edges);
        gather_accum_kernel<<<(n_nodes + 3) / 4, 256, 0, stream>>>(
            sorted_src, offsets, m, out, n_nodes);
    } else {
        hipMemsetAsync(d_out, 0, (size_t)out_size * sizeof(float), stream);
        long long total_threads = (long long)n_edges * 16;
        int scat_blocks = (int)((total_threads + 255) / 256);
        edge_scatter_kernel<<<scat_blocks, 256, 0, stream>>>(src, dst, m, out, n_edges);
    }
}

// Round 5
// 243.622 us; speedup vs baseline: 3.3336x; 1.1465x over previous
//
#include <hip/hip_runtime.h>
#include <hip/hip_bf16.h>

#define D 64
#define SCAN_TILE 1024   // elements per scan block (256 threads x 4)

// ---------- Kernel 1: m[n][:] = relu(x[n][:] @ W + b) ----------
// One wave per row. W column `lane` lives in 64 VGPRs; x row is read with
// wave-uniform float4 loads (single coalesced request per load, no LDS pipe).
__global__ __launch_bounds__(256) void node_mlp_kernel(
    const float* __restrict__ x, const float* __restrict__ W,
    const float* __restrict__ b, float* __restrict__ m, int n_nodes) {
    const int lane = threadIdx.x & 63;

    // Preload W[:, lane] into registers (64 coalesced loads, amortized over ~24 rows)
    float w[D];
    #pragma unroll
    for (int k = 0; k < D; ++k) w[k] = W[k * D + lane];
    const float bias = b[lane];

    const int wave = (blockIdx.x * blockDim.x + threadIdx.x) >> 6;
    const int nwaves = (gridDim.x * blockDim.x) >> 6;

    for (int row = wave; row < n_nodes; row += nwaves) {
        const float4* xr = (const float4*)(x + (size_t)row * D);
        float acc = bias;
        #pragma unroll
        for (int kk = 0; kk < D / 4; ++kk) {
            float4 xv = xr[kk];   // wave-uniform address -> broadcast, 1 request
            acc = fmaf(xv.x, w[4 * kk + 0], acc);
            acc = fmaf(xv.y, w[4 * kk + 1], acc);
            acc = fmaf(xv.z, w[4 * kk + 2], acc);
            acc = fmaf(xv.w, w[4 * kk + 3], acc);
        }
        m[(size_t)row * D + lane] = fmaxf(acc, 0.0f);
    }
}

// ---------- Kernel 2: histogram of dst ----------
__global__ __launch_bounds__(256) void hist_kernel(
    const int* __restrict__ dst, int* __restrict__ counts, int n_edges) {
    int e = blockIdx.x * 256 + threadIdx.x;
    if (e < n_edges) atomicAdd(&counts[dst[e]], 1);
}

// ---------- Scan stage 1: per-tile partial sums ----------
__global__ __launch_bounds__(256) void scan_partial_kernel(
    const int* __restrict__ counts, int* __restrict__ partials, int n) {
    __shared__ int red[4];
    int blk = blockIdx.x;
    int t = threadIdx.x;
    int base = blk * SCAN_TILE + t * 4;
    int s = 0;
    #pragma unroll
    for (int i = 0; i < 4; ++i) {
        int idx = base + i;
        if (idx < n) s += counts[idx];
    }
    #pragma unroll
    for (int off = 32; off > 0; off >>= 1) s += __shfl_down(s, off);
    if ((t & 63) == 0) red[t >> 6] = s;
    __syncthreads();
    if (t == 0) partials[blk] = red[0] + red[1] + red[2] + red[3];
}

// ---------- Scan stage 2: exclusive scan of tile partials ----------
__global__ __launch_bounds__(256) void scan_tops_kernel(
    int* __restrict__ partials, int* __restrict__ total_out, int nb, int n_nodes) {
    __shared__ int part[256];
    int t = threadIdx.x;
    int chunk = (nb + 255) / 256;
    int beg = t * chunk;
    int end = min(beg + chunk, nb);
    int s = 0;
    for (int i = beg; i < end; ++i) s += partials[i];
    part[t] = s;
    __syncthreads();
    for (int off = 1; off < 256; off <<= 1) {
        int v = (t >= off) ? part[t - off] : 0;
        __syncthreads();
        part[t] += v;
        __syncthreads();
    }
    int run = (t == 0) ? 0 : part[t - 1];
    for (int i = beg; i < end; ++i) {
        int c = partials[i];
        partials[i] = run;
        run += c;
    }
    if (t == 255) total_out[n_nodes] = part[255];  // offsets[n] = E
}

// ---------- Scan stage 3: local scan + tile offset -> offsets & cursor ----------
__global__ __launch_bounds__(256) void scan_final_kernel(
    const int* __restrict__ counts, const int* __restrict__ partials,
    int* __restrict__ offsets, int* __restrict__ cursor, int n) {
    __shared__ int tsum[256];
    int blk = blockIdx.x;
    int t = threadIdx.x;
    int base = blk * SCAN_TILE + t * 4;
    int c[4];
    int s = 0;
    #pragma unroll
    for (int i = 0; i < 4; ++i) {
        int idx = base + i;
        c[i] = (idx < n) ? counts[idx] : 0;
        s += c[i];
    }
    tsum[t] = s;
    __syncthreads();
    for (int off = 1; off < 256; off <<= 1) {
        int v = (t >= off) ? tsum[t - off] : 0;
        __syncthreads();
        tsum[t] += v;
        __syncthreads();
    }
    int run = partials[blk] + ((t == 0) ? 0 : tsum[t - 1]);
    #pragma unroll
    for (int i = 0; i < 4; ++i) {
        int idx = base + i;
        if (idx < n) {
            offsets[idx] = run;
            cursor[idx] = run;
            run += c[i];
        }
    }
}

// ---------- Kernel 4: scatter src into dst-grouped order ----------
__global__ __launch_bounds__(256) void scatter_kernel(
    const int* __restrict__ src, const int* __restrict__ dst,
    int* __restrict__ cursor, int* __restrict__ sorted_src, int n_edges) {
    int e = blockIdx.x * 256 + threadIdx.x;
    if (e >= n_edges) return;
    int d = dst[e];
    int pos = atomicAdd(&cursor[d], 1);
    sorted_src[pos] = src[e];
}

// ---------- Kernel 5: one wave per dst node — register accumulate, plain store ----------
__global__ __launch_bounds__(256) void gather_accum_kernel(
    const int* __restrict__ sorted_src, const int* __restrict__ offsets,
    const float* __restrict__ m, float* __restrict__ out, int n_nodes) {
    int node = blockIdx.x * 4 + (threadIdx.x >> 6);
    if (node >= n_nodes) return;
    int lane = threadIdx.x & 63;

    int beg = offsets[node];
    int cnt = offsets[node + 1] - beg;
    float acc = 0.0f;
    for (int base = 0; base < cnt; base += 64) {
        int idx = (base + lane < cnt) ? sorted_src[beg + base + lane] : 0;
        int lim = min(64, cnt - base);
        for (int k = 0; k < lim; ++k) {
            int s = __shfl(idx, k);
            acc += m[(size_t)s * D + lane];
        }
    }
    out[(size_t)node * D + lane] = acc;
}

// ---------- Fallback: atomic scatter (if ws too small) ----------
__global__ __launch_bounds__(256) void edge_scatter_kernel(
    const int* __restrict__ src, const int* __restrict__ dst,
    const float* __restrict__ m, float* __restrict__ out, int n_edges) {
    long long t = (long long)blockIdx.x * blockDim.x + threadIdx.x;
    int e = (int)(t >> 4);
    if (e >= n_edges) return;
    int c = (int)(t & 15) << 2;
    int s = src[e];
    int d = dst[e];
    const float4 v = *(const float4*)(m + (size_t)s * D + c);
    float* o = out + (size_t)d * D + c;
    atomicAdd(o + 0, v.x);
    atomicAdd(o + 1, v.y);
    atomicAdd(o + 2, v.z);
    atomicAdd(o + 3, v.w);
}

static inline size_t align_up(size_t v, size_t a) { return (v + a - 1) & ~(a - 1); }

extern "C" void kernel_launch(void* const* d_in, const int* in_sizes, int n_in,
                              void* d_out, int out_size, void* d_ws, size_t ws_size,
                              hipStream_t stream) {
    const float* x = (const float*)d_in[0];
    const int* edge_index = (const int*)d_in[1];   // int32 per harness contract
    const float* W = (const float*)d_in[2];
    const float* b = (const float*)d_in[3];
    float* out = (float*)d_out;

    const int n_nodes = in_sizes[0] / D;        // 50000
    const int n_edges = in_sizes[1] / 2;        // 800000
    const int* src = edge_index;                // row 0 (j, gather)
    const int* dst = edge_index + n_edges;      // row 1 (i, scatter)

    const int n_tiles = (n_nodes + SCAN_TILE - 1) / SCAN_TILE;

    // Workspace layout
    size_t off = 0;
    float* m = (float*)((char*)d_ws + off);
    off = align_up(off + (size_t)n_nodes * D * sizeof(float), 256);
    int* counts = (int*)((char*)d_ws + off);
    off = align_up(off + (size_t)n_nodes * sizeof(int), 256);
    int* offsets = (int*)((char*)d_ws + off);
    off = align_up(off + ((size_t)n_nodes + 1) * sizeof(int), 256);
    int* cursor = (int*)((char*)d_ws + off);
    off = align_up(off + (size_t)n_nodes * sizeof(int), 256);
    int* sorted_src = (int*)((char*)d_ws + off);
    off = align_up(off + (size_t)n_edges * sizeof(int), 256);
    int* partials = (int*)((char*)d_ws + off);
    off = align_up(off + (size_t)n_tiles * sizeof(int), 256);
    const size_t needed = off;

    // Node MLP: 512 blocks -> 2048 waves -> 8 waves/CU, ~24 rows/wave
    node_mlp_kernel<<<512, 256, 0, stream>>>(x, W, b, m, n_nodes);

    if (ws_size >= needed) {
        hipMemsetAsync(counts, 0, (size_t)n_nodes * sizeof(int), stream);
        int eblocks = (n_edges + 255) / 256;
        hist_kernel<<<eblocks, 256, 0, stream>>>(dst, counts, n_edges);
        scan_partial_kernel<<<n_tiles, 256, 0, stream>>>(counts, partials, n_nodes);
        scan_tops_kernel<<<1, 256, 0, stream>>>(partials, offsets, n_tiles, n_nodes);
        scan_final_kernel<<<n_tiles, 256, 0, stream>>>(counts, partials, offsets, cursor, n_nodes);
        scatter_kernel<<<eblocks, 256, 0, stream>>>(src, dst, cursor, sorted_src, n_edges);
        gather_accum_kernel<<<(n_nodes + 3) / 4, 256, 0, stream>>>(
            sorted_src, offsets, m, out, n_nodes);
    } else {
        hipMemsetAsync(d_out, 0, (size_t)out_size * sizeof(float), stream);
        long long total_threads = (long long)n_edges * 16;
        int scat_blocks = (int)((total_threads + 255) / 256);
        edge_scatter_kernel<<<scat_blocks, 256, 0, stream>>>(src, dst, m, out, n_edges);
    }
}

// Round 6
// 210.343 us; speedup vs baseline: 3.8610x; 1.1582x over previous
//
#include <hip/hip_runtime.h>
#include <hip/hip_bf16.h>

#define D 64
#define SCAN_TILE 1024   // elements per scan block (256 threads x 4)

__device__ __forceinline__ float bf2f(unsigned short u) {
    return __uint_as_float((unsigned int)u << 16);
}
__device__ __forceinline__ unsigned short f2bf(float f) {
    unsigned int u = __float_as_uint(f);
    unsigned int r = (u + 0x7fffu + ((u >> 16) & 1u)) >> 16;   // RNE
    return (unsigned short)r;
}

// ---------- Kernel 1: m[n][:] = bf16(relu(x[n][:] @ W + b)); also zeroes counts ----------
// One wave per row; W column `lane` in 64 VGPRs; x row via wave-uniform float4 loads.
__global__ __launch_bounds__(256) void node_mlp_kernel(
    const float* __restrict__ x, const float* __restrict__ W,
    const float* __restrict__ b, unsigned short* __restrict__ m,
    int* __restrict__ counts, int n_nodes) {
    // fused: zero the histogram buffer (saves a memset dispatch)
    for (int i = blockIdx.x * blockDim.x + threadIdx.x; i < n_nodes;
         i += gridDim.x * blockDim.x) counts[i] = 0;

    const int lane = threadIdx.x & 63;
    float w[D];
    #pragma unroll
    for (int k = 0; k < D; ++k) w[k] = W[k * D + lane];
    const float bias = b[lane];

    const int wave = (blockIdx.x * blockDim.x + threadIdx.x) >> 6;
    const int nwaves = (gridDim.x * blockDim.x) >> 6;

    for (int row = wave; row < n_nodes; row += nwaves) {
        const float4* xr = (const float4*)(x + (size_t)row * D);
        float acc = bias;
        #pragma unroll
        for (int kk = 0; kk < D / 4; ++kk) {
            float4 xv = xr[kk];   // wave-uniform address -> broadcast, 1 request
            acc = fmaf(xv.x, w[4 * kk + 0], acc);
            acc = fmaf(xv.y, w[4 * kk + 1], acc);
            acc = fmaf(xv.z, w[4 * kk + 2], acc);
            acc = fmaf(xv.w, w[4 * kk + 3], acc);
        }
        m[(size_t)row * D + lane] = f2bf(fmaxf(acc, 0.0f));
    }
}

// ---------- Kernel 2: histogram of dst ----------
__global__ __launch_bounds__(256) void hist_kernel(
    const int* __restrict__ dst, int* __restrict__ counts, int n_edges) {
    int e = blockIdx.x * 256 + threadIdx.x;
    if (e < n_edges) atomicAdd(&counts[dst[e]], 1);
}

// ---------- Scan stage 1: per-tile partial sums ----------
__global__ __launch_bounds__(256) void scan_partial_kernel(
    const int* __restrict__ counts, int* __restrict__ partials, int n) {
    __shared__ int red[4];
    int blk = blockIdx.x;
    int t = threadIdx.x;
    int base = blk * SCAN_TILE + t * 4;
    int s = 0;
    #pragma unroll
    for (int i = 0; i < 4; ++i) {
        int idx = base + i;
        if (idx < n) s += counts[idx];
    }
    #pragma unroll
    for (int off = 32; off > 0; off >>= 1) s += __shfl_down(s, off);
    if ((t & 63) == 0) red[t >> 6] = s;
    __syncthreads();
    if (t == 0) partials[blk] = red[0] + red[1] + red[2] + red[3];
}

// ---------- Scan stage 2: exclusive scan of tile partials ----------
__global__ __launch_bounds__(256) void scan_tops_kernel(
    int* __restrict__ partials, int* __restrict__ total_out, int nb, int n_nodes) {
    __shared__ int part[256];
    int t = threadIdx.x;
    int chunk = (nb + 255) / 256;
    int beg = t * chunk;
    int end = min(beg + chunk, nb);
    int s = 0;
    for (int i = beg; i < end; ++i) s += partials[i];
    part[t] = s;
    __syncthreads();
    for (int off = 1; off < 256; off <<= 1) {
        int v = (t >= off) ? part[t - off] : 0;
        __syncthreads();
        part[t] += v;
        __syncthreads();
    }
    int run = (t == 0) ? 0 : part[t - 1];
    for (int i = beg; i < end; ++i) {
        int c = partials[i];
        partials[i] = run;
        run += c;
    }
    if (t == 255) total_out[n_nodes] = part[255];  // offsets[n] = E
}

// ---------- Scan stage 3: local scan + tile offset -> offsets & cursor ----------
__global__ __launch_bounds__(256) void scan_final_kernel(
    const int* __restrict__ counts, const int* __restrict__ partials,
    int* __restrict__ offsets, int* __restrict__ cursor, int n) {
    __shared__ int tsum[256];
    int blk = blockIdx.x;
    int t = threadIdx.x;
    int base = blk * SCAN_TILE + t * 4;
    int c[4];
    int s = 0;
    #pragma unroll
    for (int i = 0; i < 4; ++i) {
        int idx = base + i;
        c[i] = (idx < n) ? counts[idx] : 0;
        s += c[i];
    }
    tsum[t] = s;
    __syncthreads();
    for (int off = 1; off < 256; off <<= 1) {
        int v = (t >= off) ? tsum[t - off] : 0;
        __syncthreads();
        tsum[t] += v;
        __syncthreads();
    }
    int run = partials[blk] + ((t == 0) ? 0 : tsum[t - 1]);
    #pragma unroll
    for (int i = 0; i < 4; ++i) {
        int idx = base + i;
        if (idx < n) {
            offsets[idx] = run;
            cursor[idx] = run;
            run += c[i];
        }
    }
}

// ---------- Kernel 4: scatter src into dst-grouped order ----------
__global__ __launch_bounds__(256) void scatter_kernel(
    const int* __restrict__ src, const int* __restrict__ dst,
    int* __restrict__ cursor, int* __restrict__ sorted_src, int n_edges) {
    int e = blockIdx.x * 256 + threadIdx.x;
    if (e >= n_edges) return;
    int d = dst[e];
    int pos = atomicAdd(&cursor[d], 1);
    sorted_src[pos] = src[e];
}

// ---------- Kernel 5: one wave per dst node, 4-way unrolled bf16 gather ----------
__global__ __launch_bounds__(256) void gather_accum_kernel(
    const int* __restrict__ sorted_src, const int* __restrict__ offsets,
    const unsigned short* __restrict__ m, float* __restrict__ out, int n_nodes) {
    int node = blockIdx.x * 4 + (threadIdx.x >> 6);
    if (node >= n_nodes) return;
    int lane = threadIdx.x & 63;

    int beg = offsets[node];
    int cnt = offsets[node + 1] - beg;
    float acc = 0.0f;
    for (int base = 0; base < cnt; base += 64) {
        int idx = (base + lane < cnt) ? sorted_src[beg + base + lane] : 0;
        int lim = min(64, cnt - base);
        int k = 0;
        for (; k + 4 <= lim; k += 4) {
            int s0 = __shfl(idx, k + 0);
            int s1 = __shfl(idx, k + 1);
            int s2 = __shfl(idx, k + 2);
            int s3 = __shfl(idx, k + 3);
            float v0 = bf2f(m[(size_t)s0 * D + lane]);   // 4 independent loads in flight
            float v1 = bf2f(m[(size_t)s1 * D + lane]);
            float v2 = bf2f(m[(size_t)s2 * D + lane]);
            float v3 = bf2f(m[(size_t)s3 * D + lane]);
            acc += (v0 + v1) + (v2 + v3);
        }
        for (; k < lim; ++k) {
            int s = __shfl(idx, k);
            acc += bf2f(m[(size_t)s * D + lane]);
        }
    }
    out[(size_t)node * D + lane] = acc;
}

// ---------- Fallback: atomic scatter (if ws too small) ----------
__global__ __launch_bounds__(256) void edge_scatter_kernel(
    const int* __restrict__ src, const int* __restrict__ dst,
    const unsigned short* __restrict__ m, float* __restrict__ out, int n_edges) {
    long long t = (long long)blockIdx.x * blockDim.x + threadIdx.x;
    int e = (int)(t >> 4);
    if (e >= n_edges) return;
    int c = (int)(t & 15) << 2;
    int s = src[e];
    int d = dst[e];
    const ushort4 v = *(const ushort4*)(m + (size_t)s * D + c);
    float* o = out + (size_t)d * D + c;
    atomicAdd(o + 0, bf2f(v.x));
    atomicAdd(o + 1, bf2f(v.y));
    atomicAdd(o + 2, bf2f(v.z));
    atomicAdd(o + 3, bf2f(v.w));
}

static inline size_t align_up(size_t v, size_t a) { return (v + a - 1) & ~(a - 1); }

extern "C" void kernel_launch(void* const* d_in, const int* in_sizes, int n_in,
                              void* d_out, int out_size, void* d_ws, size_t ws_size,
                              hipStream_t stream) {
    const float* x = (const float*)d_in[0];
    const int* edge_index = (const int*)d_in[1];   // int32 per harness contract
    const float* W = (const float*)d_in[2];
    const float* b = (const float*)d_in[3];
    float* out = (float*)d_out;

    const int n_nodes = in_sizes[0] / D;        // 50000
    const int n_edges = in_sizes[1] / 2;        // 800000
    const int* src = edge_index;                // row 0 (j, gather)
    const int* dst = edge_index + n_edges;      // row 1 (i, scatter)

    const int n_tiles = (n_nodes + SCAN_TILE - 1) / SCAN_TILE;

    // Workspace layout (m is now bf16)
    size_t off = 0;
    unsigned short* m = (unsigned short*)((char*)d_ws + off);
    off = align_up(off + (size_t)n_nodes * D * sizeof(unsigned short), 256);
    int* counts = (int*)((char*)d_ws + off);
    off = align_up(off + (size_t)n_nodes * sizeof(int), 256);
    int* offsets = (int*)((char*)d_ws + off);
    off = align_up(off + ((size_t)n_nodes + 1) * sizeof(int), 256);
    int* cursor = (int*)((char*)d_ws + off);
    off = align_up(off + (size_t)n_nodes * sizeof(int), 256);
    int* sorted_src = (int*)((char*)d_ws + off);
    off = align_up(off + (size_t)n_edges * sizeof(int), 256);
    int* partials = (int*)((char*)d_ws + off);
    off = align_up(off + (size_t)n_tiles * sizeof(int), 256);
    const size_t needed = off;

    // Node MLP (+ fused counts zeroing): 512 blocks -> 8 waves/CU
    node_mlp_kernel<<<512, 256, 0, stream>>>(x, W, b, m, counts, n_nodes);

    if (ws_size >= needed) {
        int eblocks = (n_edges + 255) / 256;
        hist_kernel<<<eblocks, 256, 0, stream>>>(dst, counts, n_edges);
        scan_partial_kernel<<<n_tiles, 256, 0, stream>>>(counts, partials, n_nodes);
        scan_tops_kernel<<<1, 256, 0, stream>>>(partials, offsets, n_tiles, n_nodes);
        scan_final_kernel<<<n_tiles, 256, 0, stream>>>(counts, partials, offsets, cursor, n_nodes);
        scatter_kernel<<<eblocks, 256, 0, stream>>>(src, dst, cursor, sorted_src, n_edges);
        gather_accum_kernel<<<(n_nodes + 3) / 4, 256, 0, stream>>>(
            sorted_src, offsets, m, out, n_nodes);
    } else {
        hipMemsetAsync(d_out, 0, (size_t)out_size * sizeof(float), stream);
        long long total_threads = (long long)n_edges * 16;
        int scat_blocks = (int)((total_threads + 255) / 256);
        edge_scatter_kernel<<<scat_blocks, 256, 0, stream>>>(src, dst, m, out, n_edges);
    }
}